// Round 4
// baseline (121.328 us; speedup 1.0000x reference)
//
#include <hip/hip_runtime.h>
#include <stdint.h>

// Problem constants
#define NSLICE 64               // B*C
#define N_ELEM 262144           // 64^3 per slice
#define K_TOP  131072           // ceil(0.5*N)
#define INV_KB (1.0f / (131072.0f * 16.0f))

#define NB     2048             // buckets: bits 30..20 of bits(|d|)
#define SHIFT  20

// Sampling: 4 chunks of 1024 contiguous elements per slice = 1/64 of data
#define SNCH    4
#define SSTRIDE (N_ELEM / SNCH)   // 65536
#define K_S     (K_TOP / 64)      // 2048 (sampled-rank target)
#define MARG    256               // ~8 sigma of sampled-rank noise

#define NW     8                // window buckets, register-resident
#define CPB    32               // blocks per slice in main pass
#define CHUNK  (N_ELEM / CPB)   // 8192
#define BLK    256

__device__ __forceinline__ unsigned int absbits(float d) {
    return __float_as_uint(d) & 0x7fffffffu;
}

// ---- 1. Sampled histogram + window select, one block per slice ------------
// Also zeroes this slice's aux accumulators (no hipMemsetAsync needed).
__global__ __launch_bounds__(BLK) void k_swin(const float* __restrict__ in,
                                              const float* __restrict__ lab,
                                              unsigned int* __restrict__ bstart,
                                              unsigned int* __restrict__ gwc,
                                              float* __restrict__ gws,
                                              float* __restrict__ sliceS,
                                              unsigned int* __restrict__ sliceC) {
    __shared__ unsigned int hc[NB];
    __shared__ unsigned int part[BLK];
    __shared__ unsigned int pref[BLK];
    const int tid = threadIdx.x;
    const int slice = blockIdx.x;
    for (int i = tid; i < NB; i += BLK) hc[i] = 0u;
    if (tid < NW) { gwc[slice * NW + tid] = 0u; gws[slice * NW + tid] = 0.0f; }
    if (tid == NW) sliceS[slice] = 0.0f;
    if (tid == NW + 1) sliceC[slice] = 0u;
    __syncthreads();
#pragma unroll
    for (int j = 0; j < SNCH; ++j) {
        const long base = (long)slice * N_ELEM + (long)j * SSTRIDE;
        const float4 a = ((const float4*)(in + base))[tid];
        const float4 b = ((const float4*)(lab + base))[tid];
        atomicAdd(&hc[absbits(a.x - b.x) >> SHIFT], 1u);
        atomicAdd(&hc[absbits(a.y - b.y) >> SHIFT], 1u);
        atomicAdd(&hc[absbits(a.z - b.z) >> SHIFT], 1u);
        atomicAdd(&hc[absbits(a.w - b.w) >> SHIFT], 1u);
    }
    __syncthreads();
    // descending suffix scan; pick first bucket where cum >= K_S - MARG
    const int G = NB / BLK;   // 8 buckets per thread
    unsigned int loc[NB / BLK];
    unsigned int s = 0;
#pragma unroll
    for (int j = 0; j < G; ++j) {
        loc[j] = hc[NB - 1 - (tid * G + j)];
        s += loc[j];
    }
    part[tid] = s;
    __syncthreads();
    if (tid == 0) {
        unsigned int c = 0;
        for (int i = 0; i < BLK; ++i) { pref[i] = c; c += part[i]; }
    }
    __syncthreads();
    const unsigned int target = K_S - MARG;
    unsigned int cum = pref[tid];
#pragma unroll
    for (int j = 0; j < G; ++j) {
        unsigned int nc = cum + loc[j];
        if (cum < target && nc >= target)
            bstart[slice] = (unsigned int)(NB - 1 - (tid * G + j));
        cum = nc;
    }
}

// ---- 2. Main pass: all accumulation in registers, no LDS in hot loop ------
__global__ __launch_bounds__(BLK) void k_main(const float* __restrict__ in,
                                              const float* __restrict__ lab,
                                              const unsigned int* __restrict__ bstart,
                                              unsigned int* __restrict__ gwc,
                                              float* __restrict__ gws,
                                              float* __restrict__ sliceS,
                                              unsigned int* __restrict__ sliceC) {
    const int tid = threadIdx.x;
    const int slice = blockIdx.y;
    const int bs = (int)bstart[slice];
    const long base = (long)slice * N_ELEM + (long)blockIdx.x * CHUNK;
    const float4* a4 = (const float4*)(in + base);
    const float4* b4 = (const float4*)(lab + base);

    float S = 0.0f;
    unsigned int C = 0u;
    float wS[NW];
    unsigned int wC[NW];
#pragma unroll
    for (int k = 0; k < NW; ++k) { wS[k] = 0.0f; wC[k] = 0u; }

    for (int i = tid; i < CHUNK / 4; i += 2 * BLK) {   // 4 iters, 2 quads each
        float4 a0 = a4[i];
        float4 b0 = b4[i];
        float4 a1 = a4[i + BLK];
        float4 b1 = b4[i + BLK];
        float d[8] = {a0.x - b0.x, a0.y - b0.y, a0.z - b0.z, a0.w - b0.w,
                      a1.x - b1.x, a1.y - b1.y, a1.z - b1.z, a1.w - b1.w};
#pragma unroll
        for (int j = 0; j < 8; ++j) {
            const float sq = d[j] * d[j];
            const int p = (int)(absbits(d[j]) >> SHIFT);
            const bool above = (p > bs);
            S += above ? sq : 0.0f;
            C += above ? 1u : 0u;
#pragma unroll
            for (int k = 0; k < NW; ++k) {      // static-indexed, predicated
                const bool h = (p == bs - k);
                wC[k] += h ? 1u : 0u;
                wS[k] += h ? sq : 0.0f;
            }
        }
    }
    // wave-level shuffle reduce of all 18 accumulators (once per block)
#pragma unroll
    for (int off = 32; off > 0; off >>= 1) {
        S += __shfl_down(S, off);
        C += __shfl_down(C, off);
#pragma unroll
        for (int k = 0; k < NW; ++k) {
            wS[k] += __shfl_down(wS[k], off);
            wC[k] += __shfl_down(wC[k], off);
        }
    }
    if ((tid & 63) == 0) {   // one lane per wave -> global atomics
        atomicAdd(&sliceS[slice], S);
        atomicAdd(&sliceC[slice], C);
#pragma unroll
        for (int k = 0; k < NW; ++k) {
            if (wC[k]) {
                atomicAdd(&gwc[slice * NW + k], wC[k]);
                atomicAdd(&gws[slice * NW + k], wS[k]);
            }
        }
    }
}

// ---- 3. Final: walk 8-bucket window, interpolate partial bucket -----------
__global__ __launch_bounds__(64) void k_final(const unsigned int* __restrict__ gwc,
                                              const float* __restrict__ gws,
                                              const unsigned int* __restrict__ bstart,
                                              const float* __restrict__ sliceS,
                                              const unsigned int* __restrict__ sliceC,
                                              float* __restrict__ out) {
    const int t = threadIdx.x;   // one lane per slice
    float S = sliceS[t];
    unsigned int cum = sliceC[t];
    const int bs = (int)bstart[t];
    const unsigned int* wc = gwc + t * NW;
    const float* ws = gws + t * NW;

    if (cum >= K_TOP) {
        S *= (float)K_TOP / (float)cum;        // grace: window top too low
    } else {
        bool done = false;
#pragma unroll
        for (int i = 0; i < NW; ++i) {
            if (done) continue;
            const unsigned int c = wc[i];
            if (c == 0u) continue;
            if (cum + c >= K_TOP) {
                const unsigned int r = K_TOP - cum;
                const float m = ws[i] / (float)c;
                const int p = (bs - i) > 0 ? (bs - i) : 0;
                const float lo = __uint_as_float((unsigned int)p << SHIFT);
                const float hi = __uint_as_float((unsigned int)(p + 1) << SHIFT);
                const float span = hi * hi - lo * lo;
                const float f = (float)r / (float)c;
                float ev = m + 0.5f * (1.0f - f) * span;   // mean of top-f part
                ev = fminf(ev, hi * hi);
                ev = fmaxf(ev, m);
                S += (float)r * ev;
                cum = K_TOP;
                done = true;
            } else {
                S += ws[i];
                cum += c;
            }
        }
        if (cum < K_TOP) {                      // grace: window bottom too high
            const int p = (bs - (NW - 1)) > 0 ? (bs - (NW - 1)) : 0;
            const float lo = __uint_as_float((unsigned int)p << SHIFT);
            S += (float)(K_TOP - cum) * lo * lo;
        }
    }
    // 64-lane reduce, single store (no memset of d_out needed)
#pragma unroll
    for (int off = 32; off > 0; off >>= 1) S += __shfl_down(S, off);
    if (t == 0) out[0] = S * INV_KB;
}

// ---------------------------------------------------------------------------
extern "C" void kernel_launch(void* const* d_in, const int* in_sizes, int n_in,
                              void* d_out, int out_size, void* d_ws, size_t ws_size,
                              hipStream_t stream) {
    const float* in = (const float*)d_in[0];
    const float* lab = (const float*)d_in[1];
    float* out = (float*)d_out;

    unsigned char* w = (unsigned char*)d_ws;
    // ws layout (tiny; all zeroed in-stream by k_swin):
    //  [0, 2K)        gwc    : 64*8 u32
    //  [2K, 4K)       gws    : 64*8 f32
    //  [4K, 4K+256)   sliceS : 64 f32
    //  [+256, +512)   sliceC : 64 u32
    //  [+512, +768)   bstart : 64 u32 (always written by k_swin)
    unsigned int* gwc = (unsigned int*)(w);
    float* gws = (float*)(w + 2048);
    float* sliceS = (float*)(w + 4096);
    unsigned int* sliceC = (unsigned int*)(w + 4096 + 256);
    unsigned int* bstart = (unsigned int*)(w + 4096 + 512);

    k_swin<<<NSLICE, BLK, 0, stream>>>(in, lab, bstart, gwc, gws, sliceS, sliceC);
    k_main<<<dim3(CPB, NSLICE), BLK, 0, stream>>>(in, lab, bstart, gwc, gws, sliceS, sliceC);
    k_final<<<1, 64, 0, stream>>>(gwc, gws, bstart, sliceS, sliceC, out);
}

// Round 5
// 83.299 us; speedup vs baseline: 1.4565x; 1.4565x over previous
//
#include <hip/hip_runtime.h>
#include <stdint.h>

// Problem constants
#define NSLICE 64               // B*C
#define N_ELEM 262144           // 64^3 per slice
#define K_TOP  131072           // ceil(0.5*N)
#define INV_KB (1.0f / (131072.0f * 16.0f))

#define NB     2048             // sample buckets: bits 30..20 of bits(|d|)
#define SHIFT  20

// Sampling: 4 chunks of 1024 contiguous elements per slice = 1/64 of data
#define SNCH    4
#define SSTRIDE (N_ELEM / SNCH)   // 65536
#define RANK_A  2048              // ascending 0-indexed sampled rank of k-th largest

#define CPB    32               // blocks per slice in main pass (grid = 2048)
#define CHUNK  (N_ELEM / CPB)   // 8192
#define BLK    256

__device__ __forceinline__ unsigned int absbits(float d) {
    return __float_as_uint(d) & 0x7fffffffu;
}

// ---- 1. Sampled histogram -> interpolated scalar threshold t'^2 -----------
// One block per slice. Also zero-inits the slice accumulators.
__global__ __launch_bounds__(BLK) void k_thresh(const float* __restrict__ in,
                                                const float* __restrict__ lab,
                                                float* __restrict__ t2arr,
                                                float* __restrict__ sliceS,
                                                unsigned int* __restrict__ sliceC) {
    __shared__ unsigned int hc[NB];
    __shared__ unsigned int part[BLK];
    __shared__ unsigned int pref[BLK];
    const int tid = threadIdx.x;
    const int slice = blockIdx.x;
    for (int i = tid; i < NB; i += BLK) hc[i] = 0u;
    if (tid == 0) sliceS[slice] = 0.0f;
    if (tid == 1) sliceC[slice] = 0u;
    __syncthreads();
#pragma unroll
    for (int j = 0; j < SNCH; ++j) {
        const long base = (long)slice * N_ELEM + (long)j * SSTRIDE;
        const float4 a = ((const float4*)(in + base))[tid];
        const float4 b = ((const float4*)(lab + base))[tid];
        atomicAdd(&hc[absbits(a.x - b.x) >> SHIFT], 1u);
        atomicAdd(&hc[absbits(a.y - b.y) >> SHIFT], 1u);
        atomicAdd(&hc[absbits(a.z - b.z) >> SHIFT], 1u);
        atomicAdd(&hc[absbits(a.w - b.w) >> SHIFT], 1u);
    }
    __syncthreads();
    // ascending scan; thread t owns buckets [t*8, t*8+8)
    const int G = NB / BLK;   // 8
    unsigned int loc[NB / BLK];
    unsigned int s = 0;
#pragma unroll
    for (int j = 0; j < G; ++j) {
        loc[j] = hc[tid * G + j];
        s += loc[j];
    }
    part[tid] = s;
    __syncthreads();
    if (tid == 0) {
        unsigned int c = 0;
        for (int i = 0; i < BLK; ++i) { pref[i] = c; c += part[i]; }
    }
    __syncthreads();
    unsigned int cum = pref[tid];
#pragma unroll
    for (int j = 0; j < G; ++j) {
        const unsigned int c = loc[j];
        if (cum <= RANK_A && RANK_A < cum + c) {
            // interpolate within bucket p: bits are linear in value (same exp)
            const unsigned int p = (unsigned int)(tid * G + j);
            const float f = (float)(RANK_A - cum) / (float)c;
            const unsigned int tbits = (p << SHIFT)
                                     + (unsigned int)(f * (float)(1u << SHIFT));
            const float t = __uint_as_float(tbits);
            t2arr[slice] = t * t;
        }
        cum += c;
    }
}

// ---- 2. Main streaming pass: 6 VALU/element, no LDS, no branching ---------
__global__ __launch_bounds__(BLK) void k_main(const float* __restrict__ in,
                                              const float* __restrict__ lab,
                                              const float* __restrict__ t2arr,
                                              float* __restrict__ sliceS,
                                              unsigned int* __restrict__ sliceC) {
    const int tid = threadIdx.x;
    const int slice = blockIdx.y;
    const float t2 = t2arr[slice];
    const long base = (long)slice * N_ELEM + (long)blockIdx.x * CHUNK;
    const float4* a4 = (const float4*)(in + base);
    const float4* b4 = (const float4*)(lab + base);

    float S0 = 0.0f, S1 = 0.0f;
    unsigned int C0 = 0u, C1 = 0u;
#pragma unroll 2
    for (int i = tid; i < CHUNK / 4; i += 2 * BLK) {   // exactly 4 iterations
        const float4 a0 = a4[i];
        const float4 b0 = b4[i];
        const float4 a1 = a4[i + BLK];
        const float4 b1 = b4[i + BLK];
        {
            float d = a0.x - b0.x; float sq = d * d; bool g = sq > t2;
            S0 += g ? sq : 0.0f; C0 += g ? 1u : 0u;
        }
        {
            float d = a0.y - b0.y; float sq = d * d; bool g = sq > t2;
            S1 += g ? sq : 0.0f; C1 += g ? 1u : 0u;
        }
        {
            float d = a0.z - b0.z; float sq = d * d; bool g = sq > t2;
            S0 += g ? sq : 0.0f; C0 += g ? 1u : 0u;
        }
        {
            float d = a0.w - b0.w; float sq = d * d; bool g = sq > t2;
            S1 += g ? sq : 0.0f; C1 += g ? 1u : 0u;
        }
        {
            float d = a1.x - b1.x; float sq = d * d; bool g = sq > t2;
            S0 += g ? sq : 0.0f; C0 += g ? 1u : 0u;
        }
        {
            float d = a1.y - b1.y; float sq = d * d; bool g = sq > t2;
            S1 += g ? sq : 0.0f; C1 += g ? 1u : 0u;
        }
        {
            float d = a1.z - b1.z; float sq = d * d; bool g = sq > t2;
            S0 += g ? sq : 0.0f; C0 += g ? 1u : 0u;
        }
        {
            float d = a1.w - b1.w; float sq = d * d; bool g = sq > t2;
            S1 += g ? sq : 0.0f; C1 += g ? 1u : 0u;
        }
    }
    float S = S0 + S1;
    unsigned int C = C0 + C1;
#pragma unroll
    for (int off = 32; off > 0; off >>= 1) {
        S += __shfl_down(S, off);
        C += __shfl_down(C, off);
    }
    if ((tid & 63) == 0) {      // one pair of global atomics per wave
        atomicAdd(&sliceS[slice], S);
        atomicAdd(&sliceC[slice], C);
    }
}

// ---- 3. Final: boundary-corrected estimator, 64-lane reduce ---------------
__global__ __launch_bounds__(64) void k_final(const float* __restrict__ sliceS,
                                              const unsigned int* __restrict__ sliceC,
                                              const float* __restrict__ t2arr,
                                              float* __restrict__ out) {
    const int t = threadIdx.x;   // one lane per slice
    // S + (k - C) * t'^2  — first-order exact for C above OR below k
    float S = sliceS[t] + ((float)K_TOP - (float)sliceC[t]) * t2arr[t];
#pragma unroll
    for (int off = 32; off > 0; off >>= 1) S += __shfl_down(S, off);
    if (t == 0) out[0] = S * INV_KB;
}

// ---------------------------------------------------------------------------
extern "C" void kernel_launch(void* const* d_in, const int* in_sizes, int n_in,
                              void* d_out, int out_size, void* d_ws, size_t ws_size,
                              hipStream_t stream) {
    const float* in = (const float*)d_in[0];
    const float* lab = (const float*)d_in[1];
    float* out = (float*)d_out;

    unsigned char* w = (unsigned char*)d_ws;
    // ws layout (all written in-stream; no memsets needed):
    //  [0, 256)       t2arr  : 64 f32 (always written by k_thresh)
    //  [256, 512)     sliceS : 64 f32 (zeroed by k_thresh)
    //  [512, 768)     sliceC : 64 u32 (zeroed by k_thresh)
    float* t2arr = (float*)(w);
    float* sliceS = (float*)(w + 256);
    unsigned int* sliceC = (unsigned int*)(w + 512);

    k_thresh<<<NSLICE, BLK, 0, stream>>>(in, lab, t2arr, sliceS, sliceC);
    k_main<<<dim3(CPB, NSLICE), BLK, 0, stream>>>(in, lab, t2arr, sliceS, sliceC);
    k_final<<<1, 64, 0, stream>>>(sliceS, sliceC, t2arr, out);
}

// Round 6
// 39.896 us; speedup vs baseline: 3.0411x; 2.0879x over previous
//
#include <hip/hip_runtime.h>
#include <stdint.h>

// Problem constants
#define NSLICE 64               // B*C
#define N_ELEM 262144           // 64^3 per slice
#define K_TOP  131072           // ceil(0.5*N)
#define INV_KB (1.0f / (131072.0f * 16.0f))

#define NB     2048             // sample buckets: bits 30..20 of bits(|d|)
#define SHIFT  20

// Sampling: 4 chunks of 1024 contiguous elements per slice = 1/64 of data
#define SNCH    4
#define SSTRIDE (N_ELEM / SNCH)   // 65536
#define RANK_A  2048              // ascending 0-indexed sampled rank of k-th largest

// Main pass: few long streams. 8 blocks/slice -> 512 blocks = 2/CU.
#define CPB    8
#define CHUNK  (N_ELEM / CPB)   // 32768 elements = 128 KB per array per block
#define BLK    256

__device__ __forceinline__ unsigned int absbits(float d) {
    return __float_as_uint(d) & 0x7fffffffu;
}

// ---- 1. Sampled histogram -> interpolated scalar threshold t'^2 -----------
// One block per slice. Also zero-inits the slice accumulators.
__global__ __launch_bounds__(BLK) void k_thresh(const float* __restrict__ in,
                                                const float* __restrict__ lab,
                                                float* __restrict__ t2arr,
                                                float* __restrict__ sliceS,
                                                unsigned int* __restrict__ sliceC) {
    __shared__ unsigned int hc[NB];
    __shared__ unsigned int part[BLK];
    __shared__ unsigned int pref[BLK];
    const int tid = threadIdx.x;
    const int slice = blockIdx.x;
    for (int i = tid; i < NB; i += BLK) hc[i] = 0u;
    if (tid == 0) sliceS[slice] = 0.0f;
    if (tid == 1) sliceC[slice] = 0u;
    __syncthreads();
#pragma unroll
    for (int j = 0; j < SNCH; ++j) {
        const long base = (long)slice * N_ELEM + (long)j * SSTRIDE;
        const float4 a = ((const float4*)(in + base))[tid];
        const float4 b = ((const float4*)(lab + base))[tid];
        atomicAdd(&hc[absbits(a.x - b.x) >> SHIFT], 1u);
        atomicAdd(&hc[absbits(a.y - b.y) >> SHIFT], 1u);
        atomicAdd(&hc[absbits(a.z - b.z) >> SHIFT], 1u);
        atomicAdd(&hc[absbits(a.w - b.w) >> SHIFT], 1u);
    }
    __syncthreads();
    // ascending scan; thread t owns buckets [t*8, t*8+8)
    const int G = NB / BLK;   // 8
    unsigned int loc[NB / BLK];
    unsigned int s = 0;
#pragma unroll
    for (int j = 0; j < G; ++j) {
        loc[j] = hc[tid * G + j];
        s += loc[j];
    }
    part[tid] = s;
    __syncthreads();
    if (tid == 0) {
        unsigned int c = 0;
        for (int i = 0; i < BLK; ++i) { pref[i] = c; c += part[i]; }
    }
    __syncthreads();
    unsigned int cum = pref[tid];
#pragma unroll
    for (int j = 0; j < G; ++j) {
        const unsigned int c = loc[j];
        if (cum <= RANK_A && RANK_A < cum + c) {
            // interpolate within bucket p: bits are linear in value (same exp)
            const unsigned int p = (unsigned int)(tid * G + j);
            const float f = (float)(RANK_A - cum) / (float)c;
            const unsigned int tbits = (p << SHIFT)
                                     + (unsigned int)(f * (float)(1u << SHIFT));
            const float t = __uint_as_float(tbits);
            t2arr[slice] = t * t;
        }
        cum += c;
    }
}

// ---- 2. Main streaming pass: long per-block streams, no LDS, no branch ----
__global__ __launch_bounds__(BLK) void k_main(const float* __restrict__ in,
                                              const float* __restrict__ lab,
                                              const float* __restrict__ t2arr,
                                              float* __restrict__ sliceS,
                                              unsigned int* __restrict__ sliceC) {
    const int tid = threadIdx.x;
    const int slice = blockIdx.y;
    const float t2 = t2arr[slice];
    const long base = (long)slice * N_ELEM + (long)blockIdx.x * CHUNK;
    const float4* a4 = (const float4*)(in + base);
    const float4* b4 = (const float4*)(lab + base);

    float S0 = 0.0f, S1 = 0.0f;
    unsigned int C0 = 0u, C1 = 0u;
#pragma unroll 4
    for (int i = tid; i < CHUNK / 4; i += BLK) {   // 32 iterations
        const float4 a = a4[i];
        const float4 b = b4[i];
        {
            float d = a.x - b.x; float sq = d * d; bool g = sq > t2;
            S0 += g ? sq : 0.0f; C0 += g ? 1u : 0u;
        }
        {
            float d = a.y - b.y; float sq = d * d; bool g = sq > t2;
            S1 += g ? sq : 0.0f; C1 += g ? 1u : 0u;
        }
        {
            float d = a.z - b.z; float sq = d * d; bool g = sq > t2;
            S0 += g ? sq : 0.0f; C0 += g ? 1u : 0u;
        }
        {
            float d = a.w - b.w; float sq = d * d; bool g = sq > t2;
            S1 += g ? sq : 0.0f; C1 += g ? 1u : 0u;
        }
    }
    float S = S0 + S1;
    unsigned int C = C0 + C1;
#pragma unroll
    for (int off = 32; off > 0; off >>= 1) {
        S += __shfl_down(S, off);
        C += __shfl_down(C, off);
    }
    if ((tid & 63) == 0) {      // one pair of global atomics per wave
        atomicAdd(&sliceS[slice], S);
        atomicAdd(&sliceC[slice], C);
    }
}

// ---- 3. Final: boundary-corrected estimator, 64-lane reduce ---------------
__global__ __launch_bounds__(64) void k_final(const float* __restrict__ sliceS,
                                              const unsigned int* __restrict__ sliceC,
                                              const float* __restrict__ t2arr,
                                              float* __restrict__ out) {
    const int t = threadIdx.x;   // one lane per slice
    // S + (k - C) * t'^2  — first-order exact for C above OR below k
    float S = sliceS[t] + ((float)K_TOP - (float)sliceC[t]) * t2arr[t];
#pragma unroll
    for (int off = 32; off > 0; off >>= 1) S += __shfl_down(S, off);
    if (t == 0) out[0] = S * INV_KB;
}

// ---------------------------------------------------------------------------
extern "C" void kernel_launch(void* const* d_in, const int* in_sizes, int n_in,
                              void* d_out, int out_size, void* d_ws, size_t ws_size,
                              hipStream_t stream) {
    const float* in = (const float*)d_in[0];
    const float* lab = (const float*)d_in[1];
    float* out = (float*)d_out;

    unsigned char* w = (unsigned char*)d_ws;
    // ws layout (all written in-stream; no memsets needed):
    //  [0, 256)       t2arr  : 64 f32 (always written by k_thresh)
    //  [256, 512)     sliceS : 64 f32 (zeroed by k_thresh)
    //  [512, 768)     sliceC : 64 u32 (zeroed by k_thresh)
    float* t2arr = (float*)(w);
    float* sliceS = (float*)(w + 256);
    unsigned int* sliceC = (unsigned int*)(w + 512);

    k_thresh<<<NSLICE, BLK, 0, stream>>>(in, lab, t2arr, sliceS, sliceC);
    k_main<<<dim3(CPB, NSLICE), BLK, 0, stream>>>(in, lab, t2arr, sliceS, sliceC);
    k_final<<<1, 64, 0, stream>>>(sliceS, sliceC, t2arr, out);
}